// Round 8
// baseline (146.441 us; speedup 1.0000x reference)
//
#include <hip/hip_runtime.h>
#include <math.h>

#define HWC 1024      // H*W
#define NB  32        // batch
#define GH  32
#define GW  32
#define NPHASE 7

// d_ws layout (bytes)
#define WS_BAR   0                           // unsigned bar[32] (zeroed each call)
#define WS_SWIN  256                         // unsigned swin[32][NB] solved-bit words
#define WS_STW   (WS_SWIN + 32 * NB * 4)     // unsigned stw[NPHASE][NB]

// fe LDS swizzle: flip addr bits 2-3 with bits 5-6. Involution. Makes the
// 4x ds_read_b128 scan hit 8 words/bank = the 8-cycle b128 floor (ideal).
#define FESWZ(i) ((i) ^ (((i) >> 3) & 12))

__device__ __forceinline__ float fe_expr(float g, float h, float o) {
    // EXACT reference chain: exp(-(g+h)*inv_c) * open, inv_c = 1/32 (exact scale)
    return __fmul_rn(expf(__fmul_rn(__fadd_rn(g, h), -0.03125f)), o);
}

template<int CTRL>
__device__ __forceinline__ float dppmax(float m) {
    int sh = __builtin_amdgcn_update_dpp(__float_as_int(m), __float_as_int(m), CTRL, 0xF, 0xF, false);
    return fmaxf(m, __int_as_float(sh));
}
template<int CTRL>
__device__ __forceinline__ unsigned dppand(unsigned m) {
    int sh = __builtin_amdgcn_update_dpp((int)m, (int)m, CTRL, 0xF, 0xF, false);
    return m & (unsigned)sh;
}

__global__ void dastar_init(unsigned* __restrict__ bar) {
    if (threadIdx.x < 32) bar[threadIdx.x] = 0u;
}

// One persistent block per batch; 64 threads (1 wave). State + step log in LDS.
__global__ __launch_bounds__(64)
void dastar_fused(const float* __restrict__ cm_g, const float* __restrict__ sm_g,
                  const float* __restrict__ gm_g, unsigned* __restrict__ swin,
                  unsigned* __restrict__ stw, unsigned* __restrict__ bar,
                  float* __restrict__ out)
{
    const int b   = blockIdx.x;
    const int tid = threadIdx.x;   // 0..63

    __shared__ __align__(16) float feT[HWC];   // FESWZ layout
    __shared__ __align__(16) float gg[HWC], oo[HWC], hi[HWC], cmS[HWC], hhS[HWC];
    __shared__ unsigned slog[HWC * 9];   // per-step: col4 = s, others = idxv bits
    __shared__ int goal_sh;

    // ---- init: thread owns cells 16*tid..16*tid+15 ----
    const float4* cm4 = (const float4*)(cm_g + b * HWC);
    const float4* sm4 = (const float4*)(sm_g + b * HWC);
    const float4* gm4 = (const float4*)(gm_g + b * HWC);
    float cmr[16], oor[16];
#pragma unroll
    for (int q = 0; q < 4; ++q) {
        int i4 = tid * 4 + q;
        float4 c4 = cm4[i4];
        float4 s4 = sm4[i4];
        float4 g4 = gm4[i4];
        int base = i4 * 4;
        float cv[4] = {c4.x, c4.y, c4.z, c4.w};
        float sv[4] = {s4.x, s4.y, s4.z, s4.w};
        float gv[4] = {g4.x, g4.y, g4.z, g4.w};
#pragma unroll
        for (int j = 0; j < 4; ++j) {
            int i = base + j;
            cmr[q * 4 + j] = cv[j];
            oor[q * 4 + j] = sv[j];
            cmS[i] = cv[j];
            gg[i] = 0.0f; hi[i] = 0.0f; oo[i] = sv[j];
            if (gv[j] == 1.0f) goal_sh = i;   // unique goal
        }
    }
    __syncthreads();

    const int   goal = goal_sh;
    const float gy = (float)(goal >> 5), gx = (float)(goal & 31);
#pragma unroll
    for (int k = 0; k < 16; ++k) {
        int i = tid * 16 + k;
        float dy = (float)(i >> 5) - gy;
        float dx = (float)(i & 31) - gx;
        float h  = __fmul_rn(sqrtf(__fadd_rn(__fmul_rn(dy, dy), __fmul_rn(dx, dx))), cmr[k]);
        hhS[i] = h;
        feT[FESWZ(i)] = fe_expr(0.0f, h, oor[k]);
    }
    __syncthreads();

    const int m4 = (tid >> 1) & 3;     // per-lane read-group permutation
    const int dyj = tid / 3 - 1, dxj = tid % 3 - 1;

    // prefetched scan values for the NEXT step: vq[t] holds cells cbase+4t..+3
    float4 vq0, vq1, vq2, vq3;
    {
        const float4* f4 = (const float4*)feT;
        vq0 = f4[(tid << 2) | (0 ^ m4)];
        vq1 = f4[(tid << 2) | (1 ^ m4)];
        vq2 = f4[(tid << 2) | (2 ^ m4)];
        vq3 = f4[(tid << 2) | (3 ^ m4)];
    }

    bool frozen = false, fsolved = false;
    int  fstep = 0, tstar = HWC - 1;
    unsigned word = 0u;
    int wpub = 0, t = 0, Pprev = 0;
    bool done = false;
    const int bounds[NPHASE] = {90, 106, 138, 202, 330, 586, 1024};

    for (int phase = 0; phase < NPHASE && !done; ++phase) {
        const int P = bounds[phase];

        while (!frozen && t < P) {
            // ---- local first-index argmax tree over prefetched values ----
            float v[16];
            v[0] = vq0.x; v[1] = vq0.y; v[2] = vq0.z; v[3] = vq0.w;
            v[4] = vq1.x; v[5] = vq1.y; v[6] = vq1.z; v[7] = vq1.w;
            v[8] = vq2.x; v[9] = vq2.y; v[10] = vq2.z; v[11] = vq2.w;
            v[12] = vq3.x; v[13] = vq3.y; v[14] = vq3.z; v[15] = vq3.w;
            const int cbase = tid * 16;
            float v8[8]; int i8[8];
#pragma unroll
            for (int k = 0; k < 8; ++k) {
                bool tk = v[2 * k + 1] > v[2 * k];
                v8[k] = tk ? v[2 * k + 1] : v[2 * k];
                i8[k] = cbase + 2 * k + (tk ? 1 : 0);
            }
            float v4a[4]; int i4a[4];
#pragma unroll
            for (int k = 0; k < 4; ++k) {
                bool tk = v8[2 * k + 1] > v8[2 * k];
                v4a[k] = tk ? v8[2 * k + 1] : v8[2 * k];
                i4a[k] = tk ? i8[2 * k + 1] : i8[2 * k];
            }
            float v2[2]; int i2a[2];
#pragma unroll
            for (int k = 0; k < 2; ++k) {
                bool tk = v4a[2 * k + 1] > v4a[2 * k];
                v2[k] = tk ? v4a[2 * k + 1] : v4a[2 * k];
                i2a[k] = tk ? i4a[2 * k + 1] : i4a[2 * k];
            }
            bool tk0 = v2[1] > v2[0];
            float bv = tk0 ? v2[1] : v2[0];
            int   bi = tk0 ? i2a[1] : i2a[0];

            // ---- global argmax: DPP value max; ballot picks lowest lane ----
            float m = bv;
            m = dppmax<0x111>(m);   // row_shr:1
            m = dppmax<0x112>(m);   // row_shr:2
            m = dppmax<0x114>(m);   // row_shr:4
            m = dppmax<0x118>(m);   // row_shr:8
            m = dppmax<0x142>(m);   // row_bcast:15
            m = dppmax<0x143>(m);   // row_bcast:31
            float gmax = __int_as_float(__builtin_amdgcn_readlane(__float_as_int(m), 63));
            unsigned long long bl = __ballot(bv == gmax);
            int lsel = (int)__ffsll(bl) - 1;
            if (lsel < 0) lsel = 0;                 // insurance
            const int  s      = __builtin_amdgcn_readlane(bi, lsel);
            const bool solved = (s == goal);

            // ---- unified update: ONE read group, then compute, then writes ----
            bool changed = false;
            float lidx = 0.0f;
            if (tid < 9) {
                const int  sy = s >> 5, sx = s & 31;
                const int  cy = sy + dyj, cx = sx + dxj;
                const bool ctr = (tid == 4);
                const bool inb = ctr || (cy >= 0 && cy < GH && cx >= 0 && cx < GW);
                const int  c  = (cy << 5) | cx;    // == s for center
                const int  q  = inb ? c : s;
                const float gq = gg[q], oq = oo[q], hq = hi[q];
                const float cmq = cmS[q], hhq = hhS[q];
                const float gs = gg[s];
                if (ctr) {
                    changed = (hq != 1.0f) || (!solved && oq != 0.0f);
                    hi[s] = 1.0f;
                    if (!solved) { oo[s] = 0.0f; feT[FESWZ(s)] = 0.0f; }
                } else if (inb) {
                    const float kc = (dyj != 0 && dxj != 0) ? 1.4142f : 1.0f;
                    const float g2 = __fadd_rn(gs, kc);
                    const float t1 = __fmul_rn(__fsub_rn(1.0f, oq), __fsub_rn(1.0f, hq));
                    const float t2 = __fmul_rn(oq, (gq > g2) ? 1.0f : 0.0f);
                    const float idxv = __fmul_rn(__fadd_rn(t1, t2), cmq);
                    lidx = idxv;
                    if (idxv != 0.0f) {
                        changed = true;
                        const float omi = __fsub_rn(1.0f, idxv);
                        const float gn = __fadd_rn(__fmul_rn(g2, idxv), __fmul_rn(gq, omi));
                        const float on = fminf(__fadd_rn(oq, idxv), 1.0f);
                        gg[c] = gn; oo[c] = on;
                        feT[FESWZ(c)] = fe_expr(gn, hhq, on);
                    }
                }
                slog[t * 9 + tid] = ctr ? (unsigned)s : __float_as_uint(lidx);
            }

            // ---- prefetch next step's scan: 4x ds_read_b128 (ideal bank spread) ----
            {
                const float4* f4 = (const float4*)feT;
                vq0 = f4[(tid << 2) | (0 ^ m4)];
                vq1 = f4[(tid << 2) | (1 ^ m4)];
                vq2 = f4[(tid << 2) | (2 ^ m4)];
                vq3 = f4[(tid << 2) | (3 ^ m4)];
            }

            unsigned long long chg = __ballot(changed);
            if (solved) word |= (1u << (t & 31));
            if (chg == 0ull) {   // fixed point: identical selection forever
                if (solved) word |= ~((1u << (t & 31)) - 1u);
                if (tid == 0)
                    __hip_atomic_store(&swin[wpub * NB + b], word, __ATOMIC_RELEASE, __HIP_MEMORY_SCOPE_AGENT);
                ++wpub;
                frozen = true; fsolved = solved; fstep = t;
                break;
            }
            ++t;
            if ((t & 31) == 0) {
                if (tid == 0)
                    __hip_atomic_store(&swin[wpub * NB + b], word, __ATOMIC_RELEASE, __HIP_MEMORY_SCOPE_AGENT);
                ++wpub; word = 0u;
            }
        }

        // ---- publish partial word / fills ----
        const int wEnd = (P + 31) >> 5;
        if (!frozen) {
            if (t & 31) {   // in-progress word: bits [0, t&31) are final for range [Pprev, P)
                if (tid == 0)
                    __hip_atomic_store(&swin[(t >> 5) * NB + b], word, __ATOMIC_RELEASE, __HIP_MEMORY_SCOPE_AGENT);
            }
        } else {
            unsigned fill = fsolved ? 0xFFFFFFFFu : 0u;
            if (tid == 0)
                for (int w = wpub; w < wEnd; ++w)
                    __hip_atomic_store(&swin[w * NB + b], fill, __ATOMIC_RELEASE, __HIP_MEMORY_SCOPE_AGENT);
            if (wpub < wEnd) wpub = wEnd;
        }

        // ---- status + device barrier ----
        if (tid == 0) {
            __hip_atomic_store(&stw[phase * NB + b], frozen ? (fsolved ? 1u : 2u) : 0u,
                               __ATOMIC_RELEASE, __HIP_MEMORY_SCOPE_AGENT);
            __hip_atomic_fetch_add(&bar[phase], 1u, __ATOMIC_ACQ_REL, __HIP_MEMORY_SCOPE_AGENT);
        }
        {
            unsigned guard = 0u;
            while (__hip_atomic_load(&bar[phase], __ATOMIC_ACQUIRE, __HIP_MEMORY_SCOPE_AGENT) < NB) {
                __builtin_amdgcn_s_sleep(1);
                if (++guard > 16000000u) break;   // watchdog (never hit in practice)
            }
        }

        // ---- redundant masked reduce of step range [Pprev, P) ----
        for (int w = (Pprev >> 5); w < wEnd; ++w) {
            int lo = Pprev - 32 * w; if (lo < 0) lo = 0;
            int hi2 = P - 32 * w;    if (hi2 > 32) hi2 = 32;
            unsigned mask = (hi2 == 32 ? 0xFFFFFFFFu : ((1u << hi2) - 1u))
                          & ~(lo == 0 ? 0u : ((1u << lo) - 1u));
            unsigned wv = __hip_atomic_load(&swin[w * NB + (tid & 31)], __ATOMIC_ACQUIRE, __HIP_MEMORY_SCOPE_AGENT);
            unsigned A = wv;
            A = dppand<0x111>(A); A = dppand<0x112>(A); A = dppand<0x114>(A);
            A = dppand<0x118>(A); A = dppand<0x142>(A); A = dppand<0x143>(A);
            A = (unsigned)__builtin_amdgcn_readlane((int)A, 63);
            A &= mask;
            if (A) { tstar = w * 32 + (__ffs(A) - 1); done = true; break; }
        }
        Pprev = P;
        if (!done) {
            unsigned sv = __hip_atomic_load(&stw[phase * NB + (tid & 31)], __ATOMIC_ACQUIRE, __HIP_MEMORY_SCOPE_AGENT);
            if (__ballot(sv != 0u) == 0xFFFFFFFFFFFFFFFFull) done = true;  // all frozen: tstar stays 1023
        }
    }
    __syncthreads();

    // ================= epilogue (per block, all from LDS) =================
    const int Tl = frozen ? min(tstar, fstep) : tstar;

    // hist = union of selected cells for t <= Tl
#pragma unroll
    for (int q = 0; q < 4; ++q)
        ((float4*)hi)[tid + (q << 6)] = make_float4(0.f, 0.f, 0.f, 0.f);
    __syncthreads();
    for (int tt = tid; tt <= Tl; tt += 64) hi[(int)slog[tt * 9 + 4]] = 1.0f;
    __syncthreads();
#pragma unroll
    for (int q = 0; q < 4; ++q) {
        int i4 = tid + (q << 6);
        ((float4*)(out + b * HWC))[i4] = ((const float4*)hi)[i4];
    }

    // parents replay into cmS (reused as pp); path buffer = hhS (reused as pb)
    const float goalf = (float)goal;
#pragma unroll
    for (int k = 0; k < 16; ++k) {
        int i = tid * 16 + k;
        cmS[i] = goalf;    // pp
        hhS[i] = 0.0f;     // pb
    }
    __syncthreads();
    if (tid < 9 && tid != 4) {
        for (int t0c = 0; t0c <= Tl; t0c += 16) {
            float iv[16], sv[16];
#pragma unroll
            for (int u = 0; u < 16; ++u) {
                int tt = t0c + u;
                if (tt <= Tl) {
                    iv[u] = __uint_as_float(slog[tt * 9 + tid]);
                    sv[u] = (float)(int)slog[tt * 9 + 4];
                } else {
                    iv[u] = 0.0f; sv[u] = 0.0f;
                }
            }
#pragma unroll
            for (int u = 0; u < 16; ++u) {
                if (iv[u] != 0.0f) {
                    int c = (int)sv[u] + (dyj << 5) + dxj;   // idxv!=0 implies in-bounds
                    float omi = __fsub_rn(1.0f, iv[u]);
                    cmS[c] = __fadd_rn(__fmul_rn(sv[u], iv[u]), __fmul_rn(cmS[c], omi));
                }
            }
        }
    }
    __syncthreads();

    // backtrack: tstar iterations, JAX index semantics, revisit break
    if (tid == 0) {
        hhS[goal] = 1.0f;
        int loc = (int)cmS[goal];
        for (int i2 = 0; i2 < tstar; ++i2) {
            int w = (loc < 0) ? loc + HWC : loc;              // JAX wraps negatives once
            if (w >= 0 && w < HWC) {
                if (hhS[w] == 1.0f) break;                    // revisit: chase cycles, no new cells
                hhS[w] = 1.0f;
            }
            int gidx = w < 0 ? 0 : (w > HWC - 1 ? HWC - 1 : w);
            loc = (int)cmS[gidx];
        }
    }
    __syncthreads();
#pragma unroll
    for (int q = 0; q < 4; ++q) {
        int i4 = tid + (q << 6);
        ((float4*)(out + NB * HWC + b * HWC))[i4] = ((const float4*)hhS)[i4];
    }
}

extern "C" void kernel_launch(void* const* d_in, const int* in_sizes, int n_in,
                              void* d_out, int out_size, void* d_ws, size_t ws_size,
                              hipStream_t stream)
{
    const float* cm = (const float*)d_in[0];
    const float* sm = (const float*)d_in[1];
    const float* gm = (const float*)d_in[2];
    float* out = (float*)d_out;

    unsigned* bar  = (unsigned*)((char*)d_ws + WS_BAR);
    unsigned* swin = (unsigned*)((char*)d_ws + WS_SWIN);
    unsigned* stw  = (unsigned*)((char*)d_ws + WS_STW);

    dastar_init<<<1, 64, 0, stream>>>(bar);
    dastar_fused<<<dim3(NB), dim3(64), 0, stream>>>(cm, sm, gm, swin, stw, bar, out);
}

// Round 9
// 115.639 us; speedup vs baseline: 1.2664x; 1.2664x over previous
//
#include <hip/hip_runtime.h>
#include <math.h>

#define HWC 1024      // H*W
#define NB  32        // batch
#define GH  32
#define GW  32
#define NPHASE 7

// d_ws layout (bytes)
#define WS_BAR   0                           // unsigned bar[32] (zeroed each call)
#define WS_SWIN  256                         // unsigned swin[32][NB] solved-bit words

// transposed fe storage: cell i -> phys word (i&15)*64 + (i>>4)
// scan (lane L reads feT[k*64+L]) hits bank L%32 -> 2 lanes/bank = conflict-free
#define FEIDX(i) ((((i) & 15) << 6) | ((i) >> 4))

__device__ __forceinline__ float fe_expr(float g, float h, float o) {
    // EXACT reference chain: exp(-(g+h)*inv_c) * open, inv_c = 1/32 (exact scale)
    return __fmul_rn(expf(__fmul_rn(__fadd_rn(g, h), -0.03125f)), o);
}

template<int CTRL>
__device__ __forceinline__ float dppmax(float m) {
    int sh = __builtin_amdgcn_update_dpp(__float_as_int(m), __float_as_int(m), CTRL, 0xF, 0xF, false);
    return fmaxf(m, __int_as_float(sh));
}
template<int CTRL>
__device__ __forceinline__ unsigned dppand(unsigned m) {
    int sh = __builtin_amdgcn_update_dpp((int)m, (int)m, CTRL, 0xF, 0xF, false);
    return m & (unsigned)sh;
}

__global__ void dastar_init(unsigned* __restrict__ bar) {
    if (threadIdx.x < 32) bar[threadIdx.x] = 0u;
}

// One persistent block per batch; 64 threads (1 wave). State + step log in LDS.
// No freeze detection: every batch simulates to the phase bound (reference
// semantics evolve all batches until global t* anyway; fixed points re-simulate
// identically, so output is bit-identical).
__global__ __launch_bounds__(64)
void dastar_fused(const float* __restrict__ cm_g, const float* __restrict__ sm_g,
                  const float* __restrict__ gm_g, unsigned* __restrict__ swin,
                  unsigned* __restrict__ bar, float* __restrict__ out)
{
    const int b   = blockIdx.x;
    const int tid = threadIdx.x;   // 0..63

    __shared__ __align__(16) float feT[HWC];   // FEIDX transposed layout
    __shared__ __align__(16) float gg[HWC], oo[HWC], hi[HWC], cmS[HWC], hhS[HWC];
    __shared__ unsigned slog[HWC * 9];   // per-step: col4 = s, others = idxv bits
    __shared__ int goal_sh;

    // ---- init: thread owns cells 16*tid..16*tid+15 ----
    const float4* cm4 = (const float4*)(cm_g + b * HWC);
    const float4* sm4 = (const float4*)(sm_g + b * HWC);
    const float4* gm4 = (const float4*)(gm_g + b * HWC);
    float cmr[16], oor[16];
#pragma unroll
    for (int q = 0; q < 4; ++q) {
        int i4 = tid * 4 + q;
        float4 c4 = cm4[i4];
        float4 s4 = sm4[i4];
        float4 g4 = gm4[i4];
        int base = i4 * 4;
        float cv[4] = {c4.x, c4.y, c4.z, c4.w};
        float sv[4] = {s4.x, s4.y, s4.z, s4.w};
        float gv[4] = {g4.x, g4.y, g4.z, g4.w};
#pragma unroll
        for (int j = 0; j < 4; ++j) {
            int i = base + j;
            cmr[q * 4 + j] = cv[j];
            oor[q * 4 + j] = sv[j];
            cmS[i] = cv[j];
            gg[i] = 0.0f; hi[i] = 0.0f; oo[i] = sv[j];
            if (gv[j] == 1.0f) goal_sh = i;   // unique goal
        }
    }
    __syncthreads();

    const int   goal = goal_sh;
    const float gy = (float)(goal >> 5), gx = (float)(goal & 31);
#pragma unroll
    for (int k = 0; k < 16; ++k) {
        int i = tid * 16 + k;
        float dy = (float)(i >> 5) - gy;
        float dx = (float)(i & 31) - gx;
        float h  = __fmul_rn(sqrtf(__fadd_rn(__fmul_rn(dy, dy), __fmul_rn(dx, dx))), cmr[k]);
        hhS[i] = h;
        feT[(k << 6) + tid] = fe_expr(0.0f, h, oor[k]);
    }
    __syncthreads();

    const int dyj = tid / 3 - 1, dxj = tid % 3 - 1;

    // prefetched scan values for the NEXT step (cell 16*tid+k at feT[(k<<6)+tid])
    float vn[16];
#pragma unroll
    for (int k = 0; k < 16; ++k) vn[k] = feT[(k << 6) + tid];

    int  tstar = HWC - 1;
    unsigned word = 0u;
    int wpub = 0, t = 0, Pprev = 0;
    bool done = false;
    const int bounds[NPHASE] = {90, 106, 138, 202, 330, 586, 1024};

    for (int phase = 0; phase < NPHASE && !done; ++phase) {
        const int P = bounds[phase];

        while (t < P) {
            float v[16];
#pragma unroll
            for (int k = 0; k < 16; ++k) v[k] = vn[k];

            // ---- value-only local max (pure fmax tree, no index bookkeeping) ----
            float a0 = fmaxf(v[0], v[1]),  a1 = fmaxf(v[2], v[3]);
            float a2 = fmaxf(v[4], v[5]),  a3 = fmaxf(v[6], v[7]);
            float a4 = fmaxf(v[8], v[9]),  a5 = fmaxf(v[10], v[11]);
            float a6 = fmaxf(v[12], v[13]), a7 = fmaxf(v[14], v[15]);
            float b0 = fmaxf(a0, a1), b1 = fmaxf(a2, a3);
            float b2 = fmaxf(a4, a5), b3 = fmaxf(a6, a7);
            float vmax = fmaxf(fmaxf(b0, b1), fmaxf(b2, b3));

            // ---- global value max via DPP; then first-index match ----
            float m = vmax;
            m = dppmax<0x111>(m);   // row_shr:1
            m = dppmax<0x112>(m);   // row_shr:2
            m = dppmax<0x114>(m);   // row_shr:4
            m = dppmax<0x118>(m);   // row_shr:8
            m = dppmax<0x142>(m);   // row_bcast:15
            m = dppmax<0x143>(m);   // row_bcast:31
            const float gmax = __int_as_float(__builtin_amdgcn_readlane(__float_as_int(m), 63));

            unsigned msk = 0u;
#pragma unroll
            for (int k = 0; k < 16; ++k) msk |= (v[k] == gmax) ? (1u << k) : 0u;
            const int lft = __ffs(msk) - 1;                 // garbage if msk==0 (lane not selected)
            unsigned long long bl = __ballot(msk != 0u);
            int lsel = (int)__ffsll(bl) - 1;
            if (lsel < 0) lsel = 0;                          // insurance
            const int  s      = __builtin_amdgcn_readlane(tid * 16 + lft, lsel);
            const bool solved = (s == goal);

            // ---- update: 8 neighbors + center (exact reference blend chain) ----
            if (tid < 9) {
                const int sy = s >> 5, sx = s & 31;
                if (tid == 4) {
                    hi[s] = 1.0f;
                    if (!solved) { oo[s] = 0.0f; feT[FEIDX(s)] = 0.0f; }
                    slog[t * 9 + 4] = (unsigned)s;
                } else {
                    const int  cy = sy + dyj, cx = sx + dxj;
                    const bool inb = (cy >= 0 && cy < GH && cx >= 0 && cx < GW);
                    const int  c  = (cy << 5) | cx;
                    const int  q  = inb ? c : s;
                    const float gq = gg[q], oq = oo[q], hq = hi[q];
                    const float cmq = cmS[q], hhq = hhS[q];
                    const float gs = gg[s];
                    float lidx = 0.0f;
                    if (inb) {
                        const float kc = (dyj != 0 && dxj != 0) ? 1.4142f : 1.0f;
                        const float g2 = __fadd_rn(gs, kc);
                        const float t1 = __fmul_rn(__fsub_rn(1.0f, oq), __fsub_rn(1.0f, hq));
                        const float t2 = __fmul_rn(oq, (gq > g2) ? 1.0f : 0.0f);
                        const float idxv = __fmul_rn(__fadd_rn(t1, t2), cmq);
                        lidx = idxv;
                        if (idxv != 0.0f) {
                            const float omi = __fsub_rn(1.0f, idxv);
                            const float gn = __fadd_rn(__fmul_rn(g2, idxv), __fmul_rn(gq, omi));
                            const float on = fminf(__fadd_rn(oq, idxv), 1.0f);
                            gg[c] = gn; oo[c] = on;
                            feT[FEIDX(c)] = fe_expr(gn, hhq, on);
                        }
                    }
                    slog[t * 9 + tid] = __float_as_uint(lidx);
                }
            }

            // ---- prefetch next step's scan (conflict-free strided b32) ----
#pragma unroll
            for (int k = 0; k < 16; ++k) vn[k] = feT[(k << 6) + tid];

            if (solved) word |= (1u << (t & 31));
            ++t;
            if ((t & 31) == 0) {
                if (tid == 0)
                    __hip_atomic_store(&swin[wpub * NB + b], word, __ATOMIC_RELEASE, __HIP_MEMORY_SCOPE_AGENT);
                ++wpub; word = 0u;
            }
        }

        // ---- publish partial word (bits [0, t&31) final for range [Pprev, P)) ----
        if ((t & 31) && tid == 0)
            __hip_atomic_store(&swin[(t >> 5) * NB + b], word, __ATOMIC_RELEASE, __HIP_MEMORY_SCOPE_AGENT);

        // ---- device barrier ----
        if (tid == 0)
            __hip_atomic_fetch_add(&bar[phase], 1u, __ATOMIC_ACQ_REL, __HIP_MEMORY_SCOPE_AGENT);
        {
            unsigned guard = 0u;
            while (__hip_atomic_load(&bar[phase], __ATOMIC_ACQUIRE, __HIP_MEMORY_SCOPE_AGENT) < NB) {
                __builtin_amdgcn_s_sleep(1);
                if (++guard > 16000000u) break;   // watchdog (never hit in practice)
            }
        }

        // ---- redundant masked reduce of step range [Pprev, P) ----
        const int wEnd = (P + 31) >> 5;
        for (int w = (Pprev >> 5); w < wEnd; ++w) {
            int lo = Pprev - 32 * w; if (lo < 0) lo = 0;
            int hi2 = P - 32 * w;    if (hi2 > 32) hi2 = 32;
            unsigned mask = (hi2 == 32 ? 0xFFFFFFFFu : ((1u << hi2) - 1u))
                          & ~(lo == 0 ? 0u : ((1u << lo) - 1u));
            unsigned wv = __hip_atomic_load(&swin[w * NB + (tid & 31)], __ATOMIC_ACQUIRE, __HIP_MEMORY_SCOPE_AGENT);
            unsigned A = wv;
            A = dppand<0x111>(A); A = dppand<0x112>(A); A = dppand<0x114>(A);
            A = dppand<0x118>(A); A = dppand<0x142>(A); A = dppand<0x143>(A);
            A = (unsigned)__builtin_amdgcn_readlane((int)A, 63);
            A &= mask;
            if (A) { tstar = w * 32 + (__ffs(A) - 1); done = true; break; }
        }
        Pprev = P;
    }
    __syncthreads();

    // ================= epilogue (per block, all from LDS) =================
    const int Tl = tstar;

    // hist = union of selected cells for t <= Tl
#pragma unroll
    for (int q = 0; q < 4; ++q)
        ((float4*)hi)[tid + (q << 6)] = make_float4(0.f, 0.f, 0.f, 0.f);
    __syncthreads();
    for (int tt = tid; tt <= Tl; tt += 64) hi[(int)slog[tt * 9 + 4]] = 1.0f;
    __syncthreads();
#pragma unroll
    for (int q = 0; q < 4; ++q) {
        int i4 = tid + (q << 6);
        ((float4*)(out + b * HWC))[i4] = ((const float4*)hi)[i4];
    }

    // parents replay into cmS (reused as pp); path buffer = hhS (reused as pb)
    const float goalf = (float)goal;
#pragma unroll
    for (int k = 0; k < 16; ++k) {
        int i = tid * 16 + k;
        cmS[i] = goalf;    // pp
        hhS[i] = 0.0f;     // pb
    }
    __syncthreads();
    if (tid < 9 && tid != 4) {
        for (int t0c = 0; t0c <= Tl; t0c += 16) {
            float iv[16], sv[16];
#pragma unroll
            for (int u = 0; u < 16; ++u) {
                int tt = t0c + u;
                if (tt <= Tl) {
                    iv[u] = __uint_as_float(slog[tt * 9 + tid]);
                    sv[u] = (float)(int)slog[tt * 9 + 4];
                } else {
                    iv[u] = 0.0f; sv[u] = 0.0f;
                }
            }
#pragma unroll
            for (int u = 0; u < 16; ++u) {
                if (iv[u] != 0.0f) {
                    int c = (int)sv[u] + (dyj << 5) + dxj;   // idxv!=0 implies in-bounds
                    float omi = __fsub_rn(1.0f, iv[u]);
                    cmS[c] = __fadd_rn(__fmul_rn(sv[u], iv[u]), __fmul_rn(cmS[c], omi));
                }
            }
        }
    }
    __syncthreads();

    // backtrack: tstar iterations, JAX index semantics, revisit break
    if (tid == 0) {
        hhS[goal] = 1.0f;
        int loc = (int)cmS[goal];
        for (int i2 = 0; i2 < tstar; ++i2) {
            int w = (loc < 0) ? loc + HWC : loc;              // JAX wraps negatives once
            if (w >= 0 && w < HWC) {
                if (hhS[w] == 1.0f) break;                    // revisit: chase cycles, no new cells
                hhS[w] = 1.0f;
            }
            int gidx = w < 0 ? 0 : (w > HWC - 1 ? HWC - 1 : w);
            loc = (int)cmS[gidx];
        }
    }
    __syncthreads();
#pragma unroll
    for (int q = 0; q < 4; ++q) {
        int i4 = tid + (q << 6);
        ((float4*)(out + NB * HWC + b * HWC))[i4] = ((const float4*)hhS)[i4];
    }
}

extern "C" void kernel_launch(void* const* d_in, const int* in_sizes, int n_in,
                              void* d_out, int out_size, void* d_ws, size_t ws_size,
                              hipStream_t stream)
{
    const float* cm = (const float*)d_in[0];
    const float* sm = (const float*)d_in[1];
    const float* gm = (const float*)d_in[2];
    float* out = (float*)d_out;

    unsigned* bar  = (unsigned*)((char*)d_ws + WS_BAR);
    unsigned* swin = (unsigned*)((char*)d_ws + WS_SWIN);

    dastar_init<<<1, 64, 0, stream>>>(bar);
    dastar_fused<<<dim3(NB), dim3(64), 0, stream>>>(cm, sm, gm, swin, bar, out);
}